// Round 5
// baseline (373.126 us; speedup 1.0000x reference)
//
#include <hip/hip_runtime.h>
#include <math.h>

#define B 32
#define C 512
#define CR 32          // C / R, R = 16
#define HW 3136        // 56*56
#define HW4 784        // HW / 4 (float4 per channel slice; slices 16B-aligned)
#define NCHAN (B * C)              // 16384
#define NELEM ((size_t)NCHAN * HW) // 51380224

// native vector type — required by __builtin_nontemporal_store (HIP float4 is
// a class, which the builtin rejects)
typedef float vf4 __attribute__((ext_vector_type(4)));

// Kernel 1: y[b,c] = mean over 3136 spatial elements. One block per (b,c).
// 784 float4 = 3 full 256-thread strides + 16-lane tail, hand-unrolled for MLP.
__global__ __launch_bounds__(256) void k_mean(const float* __restrict__ x,
                                              float* __restrict__ y) {
    const int cl = blockIdx.x;                     // b*C + c
    const int t  = threadIdx.x;
    const vf4* xp = (const vf4*)(x + (size_t)cl * HW);
    vf4 v0 = xp[t];
    vf4 v1 = xp[t + 256];
    vf4 v2 = xp[t + 512];
    float acc = ((v0.x + v0.y) + (v0.z + v0.w))
              + ((v1.x + v1.y) + (v1.z + v1.w))
              + ((v2.x + v2.y) + (v2.z + v2.w));
    if (t < 16) {
        vf4 v3 = xp[t + 768];
        acc += (v3.x + v3.y) + (v3.z + v3.w);
    }
    // wave (64-lane) shuffle reduction
    #pragma unroll
    for (int off = 32; off > 0; off >>= 1) acc += __shfl_down(acc, off, 64);
    __shared__ float s[4];
    const int lane = t & 63, wid = t >> 6;
    if (lane == 0) s[wid] = acc;
    __syncthreads();
    if (t == 0) {
        y[cl] = (s[0] + s[1] + s[2] + s[3]) * (1.0f / (float)HW);
    }
}

// Kernel 2: h = relu(y @ w1^T); g = sigmoid(h @ w2^T);
//           comp[b,c] = y[b,c] * (1 - g[b,c])  (exact: gate constant over HW,
//           so mean(x*(1-gate)) == (1-g)*mean(x))
// One block per batch b, 256 threads.
__global__ __launch_bounds__(256) void k_gate(const float* __restrict__ y,
                                              const float* __restrict__ w1,
                                              const float* __restrict__ w2,
                                              float* __restrict__ g,
                                              float* __restrict__ comp) {
    const int b = blockIdx.x;
    const int t = threadIdx.x;
    __shared__ float ys[C];
    __shared__ float part[CR][8];
    __shared__ float hs[CR];

    ys[t]       = y[b * C + t];
    ys[t + 256] = y[b * C + t + 256];
    __syncthreads();

    // h: 32 r-values, 8 partial-threads each (256 = 32*8), 64 c's per partial
    const int r = t >> 3, p = t & 7;
    {
        const vf4* w1v = (const vf4*)(w1 + r * C + p * 64);
        const vf4* yv  = (const vf4*)(ys + p * 64);
        float acc = 0.f;
        #pragma unroll
        for (int i = 0; i < 16; ++i) {
            vf4 a = w1v[i], q = yv[i];
            acc += a.x * q.x + a.y * q.y + a.z * q.z + a.w * q.w;
        }
        part[r][p] = acc;
    }
    __syncthreads();
    if (t < CR) {
        float h = 0.f;
        #pragma unroll
        for (int i = 0; i < 8; ++i) h += part[t][i];
        hs[t] = fmaxf(h, 0.f);   // relu
    }
    __syncthreads();

    // g + comp: 512 c's / 256 threads = 2 per thread
    for (int c = t; c < C; c += 256) {
        const vf4* w2c = (const vf4*)(w2 + c * CR);
        float z = 0.f;
        #pragma unroll
        for (int i = 0; i < 8; ++i) {
            vf4 w = w2c[i];
            z += hs[4*i] * w.x + hs[4*i+1] * w.y + hs[4*i+2] * w.z + hs[4*i+3] * w.w;
        }
        float gg = 1.0f / (1.0f + expf(-z));
        g[b * C + c]    = gg;
        comp[b * C + c] = ys[c] * (1.0f - gg);
    }
}

// Kernel 3: scaled = x * g. One block per channel: gate load is wave-uniform,
// no integer division. Non-temporal stores keep x resident in L3 for the
// re-read (x fits in 256 MiB Infinity Cache after k_mean's pass).
__global__ __launch_bounds__(256) void k_scale(const float* __restrict__ x,
                                               const float* __restrict__ g,
                                               float* __restrict__ out) {
    const int cl = blockIdx.x;                     // b*C + c
    const int t  = threadIdx.x;
    const float gg = g[cl];                        // uniform per block
    const vf4* xp = (const vf4*)(x + (size_t)cl * HW);
    vf4* op = (vf4*)(out + (size_t)cl * HW);
    vf4 v0 = xp[t];
    vf4 v1 = xp[t + 256];
    vf4 v2 = xp[t + 512];
    __builtin_nontemporal_store(v0 * gg, &op[t]);
    __builtin_nontemporal_store(v1 * gg, &op[t + 256]);
    __builtin_nontemporal_store(v2 * gg, &op[t + 512]);
    if (t < 16) {
        vf4 v3 = xp[t + 768];
        __builtin_nontemporal_store(v3 * gg, &op[t + 768]);
    }
}

extern "C" void kernel_launch(void* const* d_in, const int* in_sizes, int n_in,
                              void* d_out, int out_size, void* d_ws, size_t ws_size,
                              hipStream_t stream) {
    const float* x  = (const float*)d_in[0];
    const float* w1 = (const float*)d_in[1];
    const float* w2 = (const float*)d_in[2];
    float* scaled = (float*)d_out;                 // 51380224 floats
    float* comp   = (float*)d_out + NELEM;         // 16384 floats
    float* y = (float*)d_ws;                       // 16384 floats scratch
    float* g = y + NCHAN;                          // 16384 floats scratch

    k_mean <<<NCHAN, 256, 0, stream>>>(x, y);
    k_gate <<<B,     256, 0, stream>>>(y, w1, w2, g, comp);
    k_scale<<<NCHAN, 256, 0, stream>>>(x, g, scaled);
}